// Round 1
// 662.633 us; speedup vs baseline: 1.0546x; 1.0546x over previous
//
#include <hip/hip_runtime.h>
#include <cstdint>

// ---------------------------------------------------------------------------
// PureCorrelation: out = (mask' . relu(Q @ Kp^T)) @ Vp
//   Kp = K W1^T + b1,  Vp = V W2^T + b2,  mask' = mask with col0 true.
// R7: R6 + alpha-GEMM rewritten as 256x256 8-phase template (T1+T2+T3/T4+T5):
//   8 waves (512 thr), BK=64, 128 KiB LDS double-buffer, XOR-swizzled LDS
//   (pre-swizzled global source + swizzled ds_read), counted vmcnt(4),
//   setprio around MFMA clusters. Out-GEMM kept at m97-128^2 (N=512 would
//   leave half the CUs idle at 256^2 tiles).
// 4 graph nodes: prep -> proj -> alpha(256^2 8-phase) -> out.
// ---------------------------------------------------------------------------

typedef __bf16 bf16x8 __attribute__((ext_vector_type(8)));
typedef float f32x4 __attribute__((ext_vector_type(4)));

__device__ __forceinline__ unsigned short f2bf(float f) {
  unsigned int u = __float_as_uint(f);
  u += 0x7fffu + ((u >> 16) & 1u);
  return (unsigned short)(u >> 16);
}

// async global->LDS, 16B per lane. LDS dest is wave-uniform base + lane*16.
__device__ __forceinline__ void async_load16(const void* g, void* l) {
  __builtin_amdgcn_global_load_lds(
      (const __attribute__((address_space(1))) unsigned int*)(uintptr_t)g,
      (__attribute__((address_space(3))) unsigned int*)(unsigned int)(uintptr_t)l,
      16, 0, 0);
}

// ---------------------------------------------------------------------------
// prep: blocks [0,24576) cvt Q/K/V; [24576,25088) cvt W1/W2; rest pack mask.
// ---------------------------------------------------------------------------
__global__ void __launch_bounds__(256)
prep(const float* __restrict__ q, const float* __restrict__ k,
     const float* __restrict__ v, const float* __restrict__ w1,
     const float* __restrict__ w2, const int* __restrict__ m,
     unsigned short* __restrict__ qb, unsigned short* __restrict__ kb,
     unsigned short* __restrict__ vb, unsigned short* __restrict__ w1b,
     unsigned short* __restrict__ w2b, unsigned int* __restrict__ bits) {
  const int b = blockIdx.x, tid = threadIdx.x;
  if (b < 24576) {                       // Q/K/V fp32->bf16, 8192 blocks each
    const int which = b >> 13;
    const int idx = (b & 8191) * 256 + tid;
    const float* in = (which == 0) ? q : (which == 1) ? k : v;
    unsigned short* out = (which == 0) ? qb : (which == 1) ? kb : vb;
    float4 f = ((const float4*)in)[idx];
    ushort4 o;
    o.x = f2bf(f.x); o.y = f2bf(f.y); o.z = f2bf(f.z); o.w = f2bf(f.w);
    ((ushort4*)out)[idx] = o;
  } else if (b < 25088) {                // W1/W2 fp32->bf16, 256 blocks each
    const int which = (b - 24576) >> 8;
    const int idx = ((b - 24576) & 255) * 256 + tid;
    const float* in = (which == 0) ? w1 : w2;
    unsigned short* out = (which == 0) ? w1b : w2b;
    float4 f = ((const float4*)in)[idx];
    ushort4 o;
    o.x = f2bf(f.x); o.y = f2bf(f.y); o.z = f2bf(f.z); o.w = f2bf(f.w);
    ((ushort4*)out)[idx] = o;
  } else {                               // mask -> bits (col 0 forced true)
    const int lane = tid & 63;
    const size_t wid = (size_t)(b - 25088) * 4 + (tid >> 6);
    const size_t base = wid * 256;
    unsigned long long bl[4];
#pragma unroll
    for (int c = 0; c < 4; ++c) {
      size_t e = base + (size_t)c * 64 + lane;
      int col = (int)(e & 4095);  // S = 4096
      bl[c] = __ballot((m[e] != 0) || (col == 0));
    }
    if (lane < 8)
      bits[base / 32 + lane] = (unsigned int)(bl[lane >> 1] >> ((lane & 1) * 32));
  }
}

// ---------------------------------------------------------------------------
// proj: both E-projections in one launch. Blocks [0,512): Kp = Kb@W1^T+b1
// (M=16384,N=512). Blocks [512,1024): Vpt[b][f][s] = W2@Vb^T+b2 (M=512,N=4096,
// per batch). K=512, lda=ldb=512, BK=64 m97-pattern staging.
// ---------------------------------------------------------------------------
__global__ void __launch_bounds__(256)
proj(const unsigned short* __restrict__ Kb, const unsigned short* __restrict__ W1b,
     unsigned short* __restrict__ Kp, const float* __restrict__ b1,
     const unsigned short* __restrict__ W2b, const unsigned short* __restrict__ Vb,
     unsigned short* __restrict__ Vpt, const float* __restrict__ b2) {
  constexpr int K = 512;
  constexpr long long SE = 4096LL * 512;
  __shared__ unsigned short sA[2 * 128 * 32];
  __shared__ unsigned short sB[2 * 128 * 32];

  const int L = blockIdx.x;
  const unsigned short *Ab, *Bb;
  unsigned short* C;
  const float* bias;
  int tm0, tn0, N, epi;
  if (L < 512) {                 // Kp projection
    tn0 = (L & 3) * 128; tm0 = (L >> 2) * 128;
    Ab = Kb; Bb = W1b; C = Kp; bias = b1; N = 512; epi = 0;
  } else {                       // Vpt projection
    const int t = L - 512;
    tn0 = (t & 31) * 128; tm0 = ((t >> 5) & 3) * 128;
    const int bz = t >> 7;
    Ab = W2b; Bb = Vb + (size_t)bz * SE; C = Vpt + (size_t)bz * SE;
    bias = b2; N = 4096; epi = 1;
  }

  const int tid = threadIdx.x;
  const int lane = tid & 63, wave = tid >> 6;
  const int ldrow = lane >> 2, lcol = (lane & 3) * 8;
  const int wm = (wave >> 1) * 64, wn = (wave & 1) * 64;
  const int lr = lane & 15, lq = lane >> 4;

  f32x4 acc[4][4] = {};

  for (int k0 = 0; k0 < K; k0 += 64) {
#pragma unroll
    for (int g = 0; g < 2; ++g)
#pragma unroll
      for (int l = 0; l < 2; ++l) {
        const int row = wave * 32 + l * 16;
        async_load16(Ab + (size_t)(tm0 + row + ldrow) * K + (k0 + g * 32 + lcol),
                     &sA[g * 4096 + row * 32]);
        async_load16(Bb + (size_t)(tn0 + row + ldrow) * K + (k0 + g * 32 + lcol),
                     &sB[g * 4096 + row * 32]);
      }
    __syncthreads();
#pragma unroll
    for (int g = 0; g < 2; ++g) {
      bf16x8 af[4], bfr[4];
#pragma unroll
      for (int t = 0; t < 4; ++t) {
        af[t]  = *(const bf16x8*)&sA[g * 4096 + (wm + t * 16 + lr) * 32 + lq * 8];
        bfr[t] = *(const bf16x8*)&sB[g * 4096 + (wn + t * 16 + lr) * 32 + lq * 8];
      }
#pragma unroll
      for (int mt = 0; mt < 4; ++mt)
#pragma unroll
        for (int nt = 0; nt < 4; ++nt)
          acc[mt][nt] = __builtin_amdgcn_mfma_f32_16x16x32_bf16(af[mt], bfr[nt],
                                                                acc[mt][nt], 0, 0, 0);
    }
    __syncthreads();
  }

#pragma unroll
  for (int mt = 0; mt < 4; ++mt)
#pragma unroll
    for (int r = 0; r < 4; ++r) {
      const int mm = tm0 + wm + mt * 16 + lq * 4 + r;
#pragma unroll
      for (int nt = 0; nt < 4; ++nt) {
        const int n = tn0 + wn + nt * 16 + lr;
        float v = acc[mt][nt][r];
        v += (epi == 0) ? bias[n] : bias[mm];
        C[(size_t)mm * N + n] = f2bf(v);
      }
    }
}

// ---------------------------------------------------------------------------
// gemm256: 256x256-tile 8-phase GEMM, C = A[M,K] @ B[N,K]^T (+ epilogue).
// 512 threads = 8 waves (2M x 4N), per-wave output 128x64, BK=64, 2 K-tiles
// per iteration. LDS 128 KiB (A,B each 2 x [256][64] bf16).
// T2 swizzle: LDS[row][b] holds G[row][b ^ ((row&7)<<4)] (linear gload_lds
// dest + inverse-swizzled global source); ds_read applies the same XOR.
// T4: counted vmcnt(4) at p4/p8 only (drain 0 at last iter where prefetch
// guard empties the queue). T5: setprio(1) around each 16-MFMA quadrant.
// Region-safety: A-buf last read p3/p7, B-buf last read p2/p6; stages of the
// next tiles land strictly after (p5-p6 A, p3-p4/p7-p8 B, p1-p2 A-odd).
// EPI 2 = bitmask+relu store bf16 (alpha).
// ---------------------------------------------------------------------------
template <int EPI>
__global__ void __launch_bounds__(512, 2)
gemm256(const unsigned short* __restrict__ A, const unsigned short* __restrict__ B,
        void* __restrict__ Cout, const unsigned int* __restrict__ mbits,
        int M, int N, int K,
        long long strA, long long strB, long long strC, long long strM) {
  __shared__ unsigned short sA[2][256][64];
  __shared__ unsigned short sB[2][256][64];

  // T1: bijective XCD swizzle over flattened grid (gridDim.x % 8 == 0 here)
  int lin = blockIdx.x;
  lin = (lin & 7) * ((int)gridDim.x >> 3) + (lin >> 3);
  const int tilesN = N >> 8;
  const int tilesM = M >> 8;
  const int bx = lin % tilesN;
  const int by = (lin / tilesN) % tilesM;
  const int bz = lin / (tilesN * tilesM);

  const int tn0 = bx << 8, tm0 = by << 8;
  const unsigned short* Ab = A + (size_t)bz * strA;
  const unsigned short* Bb = B + (size_t)bz * strB;

  const int tid  = threadIdx.x;
  const int lane = tid & 63;
  const int w    = tid >> 6;   // 0..7
  const int wr   = w >> 2;     // 0..1 (M)
  const int wc   = w & 3;      // 0..3 (N)
  const int lr   = lane & 15;
  const int lq   = lane >> 4;

  // staging: one STAGE64 = 512 thr x 16B = 64 rows of 128B. Linear LDS dest
  // (base + tid*16); global source column pre-XORed so swizzled reads work.
  const int srow = tid >> 3;                          // 0..63
  const int scol = (((tid & 7) ^ (srow & 7)) << 3);   // element offset in row
  const int sdst = tid << 4;                          // byte offset in slab

#define STAGE64(bufbase, g, t0, k0, R0)                                      \
  async_load16((g) + (size_t)((t0) + (R0) + srow) * K + (k0) + scol,         \
               (char*)(bufbase) + ((R0) << 7) + sdst)

  // fragment reads (ds_read_b128) with matching XOR swizzle
  const int sxor  = (lr & 7) << 4;
  const int k0off = (lq << 4) ^ sxor;           // kk=0 byte-in-row
  const int k1off = (64 | (lq << 4)) ^ sxor;    // kk=1 byte-in-row
  const int aRow  = (wr * 128 + lr) * 128;      // byte
  const int bRow  = (wc * 64 + lr) * 128;       // byte

#define LDA(d, mh, mt2, kk)                                                  \
  (*(const bf16x8*)((const char*)sA[d] + aRow + (mh) * 8192 + (mt2) * 2048 + \
                    k##kk##off))
#define LDB(d, nh, nt2, kk)                                                  \
  (*(const bf16x8*)((const char*)sB[d] + bRow + (nh) * 4096 + (nt2) * 2048 + \
                    k##kk##off))

  f32x4 acc[8][4] = {};
  bf16x8 afr[4][2];   // current m-half of current tile
  bf16x8 bfr[4][2];   // both n-halves of current tile (abs nt index)

#define RDA(d, mh)                                                           \
  _Pragma("unroll") for (int mt2 = 0; mt2 < 4; ++mt2) {                      \
    afr[mt2][0] = LDA(d, mh, mt2, 0);                                        \
    afr[mt2][1] = LDA(d, mh, mt2, 1);                                        \
  }
#define RDB(d, nh)                                                           \
  _Pragma("unroll") for (int nt2 = 0; nt2 < 2; ++nt2) {                      \
    bfr[(nh) * 2 + nt2][0] = LDB(d, nh, nt2, 0);                             \
    bfr[(nh) * 2 + nt2][1] = LDB(d, nh, nt2, 1);                             \
  }
#define MFMAQ(mh, nh)                                                        \
  __builtin_amdgcn_s_setprio(1);                                             \
  _Pragma("unroll") for (int mt2 = 0; mt2 < 4; ++mt2)                        \
  _Pragma("unroll") for (int nt2 = 0; nt2 < 2; ++nt2) {                      \
    acc[(mh) * 4 + mt2][(nh) * 2 + nt2] =                                    \
        __builtin_amdgcn_mfma_f32_16x16x32_bf16(                             \
            afr[mt2][0], bfr[(nh) * 2 + nt2][0],                             \
            acc[(mh) * 4 + mt2][(nh) * 2 + nt2], 0, 0, 0);                   \
    acc[(mh) * 4 + mt2][(nh) * 2 + nt2] =                                    \
        __builtin_amdgcn_mfma_f32_16x16x32_bf16(                             \
            afr[mt2][1], bfr[(nh) * 2 + nt2][1],                             \
            acc[(mh) * 4 + mt2][(nh) * 2 + nt2], 0, 0, 0);                   \
  }                                                                          \
  __builtin_amdgcn_s_setprio(0);
#define BAR __builtin_amdgcn_s_barrier()

  const int nIter = K >> 7;   // 2 K-tiles of 64 per iteration

  // prologue: B(t0) -> sB0, A(t0) -> sA0, B(t1) -> sB1 (12 issues)
  STAGE64(sB[0], Bb, tn0, 0, 0);   STAGE64(sB[0], Bb, tn0, 0, 64);
  STAGE64(sB[0], Bb, tn0, 0, 128); STAGE64(sB[0], Bb, tn0, 0, 192);
  STAGE64(sA[0], Ab, tm0, 0, 0);   STAGE64(sA[0], Ab, tm0, 0, 64);
  STAGE64(sA[0], Ab, tm0, 0, 128); STAGE64(sA[0], Ab, tm0, 0, 192);
  STAGE64(sB[1], Bb, tn0, 64, 0);  STAGE64(sB[1], Bb, tn0, 64, 64);
  STAGE64(sB[1], Bb, tn0, 64, 128);STAGE64(sB[1], Bb, tn0, 64, 192);
  asm volatile("s_waitcnt vmcnt(4)" ::: "memory");  // tile0 A+B landed
  BAR;

  for (int j = 0; j < nIter; ++j) {
    const int kb = j << 7;              // k of even tile of this pair
    const bool pf = (j + 1 < nIter);    // prefetch tiles kt+2/kt+3 valid
    // ---- p1: tile kt (buf0) quad(mh0,nh0); stage A(kt+1) h0 -> sA1
    RDA(0, 0); RDB(0, 0);
    STAGE64(sA[1], Ab, tm0, kb + 64, 0);
    STAGE64(sA[1], Ab, tm0, kb + 64, 64);
    BAR; MFMAQ(0, 0); BAR;
    // ---- p2: quad(mh0,nh1); stage A(kt+1) h1
    RDB(0, 1);
    STAGE64(sA[1], Ab, tm0, kb + 64, 128);
    STAGE64(sA[1], Ab, tm0, kb + 64, 192);
    BAR; MFMAQ(0, 1); BAR;
    // ---- p3: quad(mh1,nh1); stage B(kt+2) h0 -> sB0 (B0 free after p2)
    RDA(0, 1);
    if (pf) { STAGE64(sB[0], Bb, tn0, kb + 128, 0);
              STAGE64(sB[0], Bb, tn0, kb + 128, 64); }
    BAR; MFMAQ(1, 1); BAR;
    // ---- p4: quad(mh1,nh0) (b held from p1); stage B(kt+2) h1; gate tile kt+1
    if (pf) { STAGE64(sB[0], Bb, tn0, kb + 128, 128);
              STAGE64(sB[0], Bb, tn0, kb + 128, 192); }
    BAR; MFMAQ(1, 0);
    if (pf) asm volatile("s_waitcnt vmcnt(4)" ::: "memory");
    else    asm volatile("s_waitcnt vmcnt(0)" ::: "memory");
    BAR;
    // ---- p5: tile kt+1 (buf1) quad(mh0,nh0); stage A(kt+2) h0 -> sA0
    RDA(1, 0); RDB(1, 0);
    if (pf) { STAGE64(sA[0], Ab, tm0, kb + 128, 0);
              STAGE64(sA[0], Ab, tm0, kb + 128, 64); }
    BAR; MFMAQ(0, 0); BAR;
    // ---- p6: quad(mh0,nh1); stage A(kt+2) h1
    RDB(1, 1);
    if (pf) { STAGE64(sA[0], Ab, tm0, kb + 128, 128);
              STAGE64(sA[0], Ab, tm0, kb + 128, 192); }
    BAR; MFMAQ(0, 1); BAR;
    // ---- p7: quad(mh1,nh1); stage B(kt+3) h0 -> sB1 (B1 free after p6)
    RDA(1, 1);
    if (pf) { STAGE64(sB[1], Bb, tn0, kb + 192, 0);
              STAGE64(sB[1], Bb, tn0, kb + 192, 64); }
    BAR; MFMAQ(1, 1); BAR;
    // ---- p8: quad(mh1,nh0); stage B(kt+3) h1; gate next p1 (tile kt+2)
    if (pf) { STAGE64(sB[1], Bb, tn0, kb + 192, 128);
              STAGE64(sB[1], Bb, tn0, kb + 192, 192); }
    BAR; MFMAQ(1, 0);
    asm volatile("s_waitcnt vmcnt(4)" ::: "memory");
    BAR;
  }

  // epilogue: per thread 8x4 fragments x 4 rows
#pragma unroll
  for (int mt = 0; mt < 8; ++mt) {
#pragma unroll
    for (int r = 0; r < 4; ++r) {
      const int m = tm0 + wr * 128 + mt * 16 + lq * 4 + r;
      unsigned long long w64 = 0;
      if constexpr (EPI == 2) {
        w64 = *(const unsigned long long*)&mbits[(size_t)bz * strM +
                                                 (size_t)m * (N >> 5) +
                                                 ((tn0 + wc * 64) >> 5)];
      }
#pragma unroll
      for (int nt = 0; nt < 4; ++nt) {
        const int n = tn0 + wc * 64 + nt * 16 + lr;
        float v = acc[mt][nt][r];
        if constexpr (EPI == 2) {
          v = ((w64 >> (nt * 16 + lr)) & 1ull) ? fmaxf(v, 0.f) : 0.f;
          ((unsigned short*)Cout)[(size_t)bz * strC + (size_t)m * N + n] = f2bf(v);
        } else {
          ((float*)Cout)[(size_t)bz * strC + (size_t)m * N + n] = v;
        }
      }
    }
  }
#undef STAGE64
#undef LDA
#undef LDB
#undef RDA
#undef RDB
#undef MFMAQ
#undef BAR
}

// C = A[M,K] @ B[N,K]^T (+ epilogue). Row-major, lda=K, ldb=K, ldc=N.
// EPI: 3 = plain store fp32 (final out). m97 128^2 structure.
template <int EPI>
__global__ void __launch_bounds__(256)
gemm_bt(const unsigned short* __restrict__ A, const unsigned short* __restrict__ B,
        void* __restrict__ Cout, const unsigned int* __restrict__ mbits,
        int M, int N, int K,
        long long strA, long long strB, long long strC, long long strM) {
  __shared__ unsigned short sA[2 * 128 * 32];
  __shared__ unsigned short sB[2 * 128 * 32];

  const int tid  = threadIdx.x;
  const int lane = tid & 63;
  const int wave = tid >> 6;
  const int bz   = blockIdx.z;
  const int tn0  = blockIdx.x * 128;
  const int tm0  = blockIdx.y * 128;

  const unsigned short* Ab = A + (size_t)bz * strA;
  const unsigned short* Bb = B + (size_t)bz * strB;

  const int ldrow = lane >> 2;
  const int lcol  = (lane & 3) * 8;
  const int wm = (wave >> 1) * 64;
  const int wn = (wave & 1) * 64;
  const int lr = lane & 15;
  const int lq = lane >> 4;

  f32x4 acc[4][4] = {};

  for (int k0 = 0; k0 < K; k0 += 64) {
#pragma unroll
    for (int g = 0; g < 2; ++g)
#pragma unroll
      for (int l = 0; l < 2; ++l) {
        const int row = wave * 32 + l * 16;
        async_load16(Ab + (size_t)(tm0 + row + ldrow) * K + (k0 + g * 32 + lcol),
                     &sA[g * 4096 + row * 32]);
        async_load16(Bb + (size_t)(tn0 + row + ldrow) * K + (k0 + g * 32 + lcol),
                     &sB[g * 4096 + row * 32]);
      }
    __syncthreads();
#pragma unroll
    for (int g = 0; g < 2; ++g) {
      bf16x8 af[4], bfr[4];
#pragma unroll
      for (int t = 0; t < 4; ++t) {
        af[t]  = *(const bf16x8*)&sA[g * 4096 + (wm + t * 16 + lr) * 32 + lq * 8];
        bfr[t] = *(const bf16x8*)&sB[g * 4096 + (wn + t * 16 + lr) * 32 + lq * 8];
      }
#pragma unroll
      for (int mt = 0; mt < 4; ++mt)
#pragma unroll
        for (int nt = 0; nt < 4; ++nt)
          acc[mt][nt] = __builtin_amdgcn_mfma_f32_16x16x32_bf16(af[mt], bfr[nt],
                                                                acc[mt][nt], 0, 0, 0);
    }
    __syncthreads();
  }

#pragma unroll
  for (int mt = 0; mt < 4; ++mt) {
#pragma unroll
    for (int r = 0; r < 4; ++r) {
      const int m = tm0 + wm + mt * 16 + lq * 4 + r;
#pragma unroll
      for (int nt = 0; nt < 4; ++nt) {
        const int n = tn0 + wn + nt * 16 + lr;
        float v = acc[mt][nt][r];
        ((float*)Cout)[(size_t)bz * strC + (size_t)m * N + n] = v;
      }
    }
  }
}

extern "C" void kernel_launch(void* const* d_in, const int* in_sizes, int n_in,
                              void* d_out, int out_size, void* d_ws, size_t ws_size,
                              hipStream_t stream) {
  const float* query = (const float*)d_in[0];
  const float* key   = (const float*)d_in[1];
  const float* value = (const float*)d_in[2];
  const int*   mask  = (const int*)d_in[3];
  const float* W1    = (const float*)d_in[4];
  const float* b1    = (const float*)d_in[5];
  const float* W2    = (const float*)d_in[6];
  const float* b2    = (const float*)d_in[7];
  float* out = (float*)d_out;

  constexpr int B = 4, S = 4096, E = 512;
  constexpr long long BSE = (long long)B * S * E;
  constexpr long long SE  = (long long)S * E;
  constexpr long long SS  = (long long)S * S;
  constexpr long long BSS = (long long)B * S * S;
  constexpr long long EE  = (long long)E * E;

  char* ws = (char*)d_ws;
  unsigned short* Qb   = (unsigned short*)ws;  ws += BSE * 2;
  unsigned short* Kb   = (unsigned short*)ws;  ws += BSE * 2;
  unsigned short* Vb   = (unsigned short*)ws;  ws += BSE * 2;
  unsigned short* W1b  = (unsigned short*)ws;  ws += EE * 2;
  unsigned short* W2b  = (unsigned short*)ws;  ws += EE * 2;
  unsigned short* Kp   = (unsigned short*)ws;  ws += BSE * 2;   // [B*S, E]
  unsigned short* Vpt  = (unsigned short*)ws;  ws += BSE * 2;   // [B][E][S]
  unsigned short* alph = (unsigned short*)ws;  ws += BSS * 2;   // [B][S][S]
  unsigned int*   mbit = (unsigned int*)ws;    ws += BSS / 8;   // [B][S][S/32]

  // converts + mask packing, one launch
  prep<<<dim3(24576 + 512 + 65536), 256, 0, stream>>>(
      query, key, value, W1, W2, mask, Qb, Kb, Vb, W1b, W2b, mbit);

  // both projections, one launch (1024 blocks = 4/CU)
  proj<<<dim3(1024), 256, 0, stream>>>(Kb, W1b, Kp, b1, W2b, Vb, Vpt, b2);

  // alpha = bitmask-relu(Qb @ Kp^T)  (M=N=S, K=E, per batch) — 256^2 8-phase
  gemm256<2><<<dim3((S / 256) * (S / 256) * B), 512, 0, stream>>>(
      Qb, Kp, alph, mbit, S, S, E, SE, SE, SS, SS / 32);

  // out = alpha @ Vpt^T   (M=S, N=E, K=S, per batch)
  gemm_bt<3><<<dim3(E / 128, S / 128, B), 256, 0, stream>>>(
      alph, Vpt, out, nullptr, S, E, S, SS, SE, SE, 0);
}

// Round 2
// 631.008 us; speedup vs baseline: 1.1075x; 1.0501x over previous
//
#include <hip/hip_runtime.h>
#include <cstdint>

// ---------------------------------------------------------------------------
// PureCorrelation: out = (mask' . relu(Q @ Kp^T)) @ Vp
//   Kp = K W1^T + b1,  Vp = V W2^T + b2,  mask' = mask with col0 true.
// R8: R7 + out-GEMM ported to the 8-phase structure at BM=256 x BN=128
//   (8 waves, per-wave 128x32, LDS 96 KiB, grid 256 = 1 block/CU), counted
//   vmcnt(2) derived for A=4/B=2 stage-calls per K-tile. Alpha stays on the
//   256^2 8-phase kernel. 4 graph nodes: prep -> proj -> alpha -> out.
// ---------------------------------------------------------------------------

typedef __bf16 bf16x8 __attribute__((ext_vector_type(8)));
typedef float f32x4 __attribute__((ext_vector_type(4)));

__device__ __forceinline__ unsigned short f2bf(float f) {
  unsigned int u = __float_as_uint(f);
  u += 0x7fffu + ((u >> 16) & 1u);
  return (unsigned short)(u >> 16);
}

// async global->LDS, 16B per lane. LDS dest is wave-uniform base + lane*16.
__device__ __forceinline__ void async_load16(const void* g, void* l) {
  __builtin_amdgcn_global_load_lds(
      (const __attribute__((address_space(1))) unsigned int*)(uintptr_t)g,
      (__attribute__((address_space(3))) unsigned int*)(unsigned int)(uintptr_t)l,
      16, 0, 0);
}

// ---------------------------------------------------------------------------
// prep: blocks [0,24576) cvt Q/K/V; [24576,25088) cvt W1/W2; rest pack mask.
// ---------------------------------------------------------------------------
__global__ void __launch_bounds__(256)
prep(const float* __restrict__ q, const float* __restrict__ k,
     const float* __restrict__ v, const float* __restrict__ w1,
     const float* __restrict__ w2, const int* __restrict__ m,
     unsigned short* __restrict__ qb, unsigned short* __restrict__ kb,
     unsigned short* __restrict__ vb, unsigned short* __restrict__ w1b,
     unsigned short* __restrict__ w2b, unsigned int* __restrict__ bits) {
  const int b = blockIdx.x, tid = threadIdx.x;
  if (b < 24576) {                       // Q/K/V fp32->bf16, 8192 blocks each
    const int which = b >> 13;
    const int idx = (b & 8191) * 256 + tid;
    const float* in = (which == 0) ? q : (which == 1) ? k : v;
    unsigned short* out = (which == 0) ? qb : (which == 1) ? kb : vb;
    float4 f = ((const float4*)in)[idx];
    ushort4 o;
    o.x = f2bf(f.x); o.y = f2bf(f.y); o.z = f2bf(f.z); o.w = f2bf(f.w);
    ((ushort4*)out)[idx] = o;
  } else if (b < 25088) {                // W1/W2 fp32->bf16, 256 blocks each
    const int which = (b - 24576) >> 8;
    const int idx = ((b - 24576) & 255) * 256 + tid;
    const float* in = (which == 0) ? w1 : w2;
    unsigned short* out = (which == 0) ? w1b : w2b;
    float4 f = ((const float4*)in)[idx];
    ushort4 o;
    o.x = f2bf(f.x); o.y = f2bf(f.y); o.z = f2bf(f.z); o.w = f2bf(f.w);
    ((ushort4*)out)[idx] = o;
  } else {                               // mask -> bits (col 0 forced true)
    const int lane = tid & 63;
    const size_t wid = (size_t)(b - 25088) * 4 + (tid >> 6);
    const size_t base = wid * 256;
    unsigned long long bl[4];
#pragma unroll
    for (int c = 0; c < 4; ++c) {
      size_t e = base + (size_t)c * 64 + lane;
      int col = (int)(e & 4095);  // S = 4096
      bl[c] = __ballot((m[e] != 0) || (col == 0));
    }
    if (lane < 8)
      bits[base / 32 + lane] = (unsigned int)(bl[lane >> 1] >> ((lane & 1) * 32));
  }
}

// ---------------------------------------------------------------------------
// proj: both E-projections in one launch. Blocks [0,512): Kp = Kb@W1^T+b1
// (M=16384,N=512). Blocks [512,1024): Vpt[b][f][s] = W2@Vb^T+b2 (M=512,N=4096,
// per batch). K=512, lda=ldb=512, BK=64 m97-pattern staging.
// ---------------------------------------------------------------------------
__global__ void __launch_bounds__(256)
proj(const unsigned short* __restrict__ Kb, const unsigned short* __restrict__ W1b,
     unsigned short* __restrict__ Kp, const float* __restrict__ b1,
     const unsigned short* __restrict__ W2b, const unsigned short* __restrict__ Vb,
     unsigned short* __restrict__ Vpt, const float* __restrict__ b2) {
  constexpr int K = 512;
  constexpr long long SE = 4096LL * 512;
  __shared__ unsigned short sA[2 * 128 * 32];
  __shared__ unsigned short sB[2 * 128 * 32];

  const int L = blockIdx.x;
  const unsigned short *Ab, *Bb;
  unsigned short* C;
  const float* bias;
  int tm0, tn0, N, epi;
  if (L < 512) {                 // Kp projection
    tn0 = (L & 3) * 128; tm0 = (L >> 2) * 128;
    Ab = Kb; Bb = W1b; C = Kp; bias = b1; N = 512; epi = 0;
  } else {                       // Vpt projection
    const int t = L - 512;
    tn0 = (t & 31) * 128; tm0 = ((t >> 5) & 3) * 128;
    const int bz = t >> 7;
    Ab = W2b; Bb = Vb + (size_t)bz * SE; C = Vpt + (size_t)bz * SE;
    bias = b2; N = 4096; epi = 1;
  }

  const int tid = threadIdx.x;
  const int lane = tid & 63, wave = tid >> 6;
  const int ldrow = lane >> 2, lcol = (lane & 3) * 8;
  const int wm = (wave >> 1) * 64, wn = (wave & 1) * 64;
  const int lr = lane & 15, lq = lane >> 4;

  f32x4 acc[4][4] = {};

  for (int k0 = 0; k0 < K; k0 += 64) {
#pragma unroll
    for (int g = 0; g < 2; ++g)
#pragma unroll
      for (int l = 0; l < 2; ++l) {
        const int row = wave * 32 + l * 16;
        async_load16(Ab + (size_t)(tm0 + row + ldrow) * K + (k0 + g * 32 + lcol),
                     &sA[g * 4096 + row * 32]);
        async_load16(Bb + (size_t)(tn0 + row + ldrow) * K + (k0 + g * 32 + lcol),
                     &sB[g * 4096 + row * 32]);
      }
    __syncthreads();
#pragma unroll
    for (int g = 0; g < 2; ++g) {
      bf16x8 af[4], bfr[4];
#pragma unroll
      for (int t = 0; t < 4; ++t) {
        af[t]  = *(const bf16x8*)&sA[g * 4096 + (wm + t * 16 + lr) * 32 + lq * 8];
        bfr[t] = *(const bf16x8*)&sB[g * 4096 + (wn + t * 16 + lr) * 32 + lq * 8];
      }
#pragma unroll
      for (int mt = 0; mt < 4; ++mt)
#pragma unroll
        for (int nt = 0; nt < 4; ++nt)
          acc[mt][nt] = __builtin_amdgcn_mfma_f32_16x16x32_bf16(af[mt], bfr[nt],
                                                                acc[mt][nt], 0, 0, 0);
    }
    __syncthreads();
  }

#pragma unroll
  for (int mt = 0; mt < 4; ++mt)
#pragma unroll
    for (int r = 0; r < 4; ++r) {
      const int mm = tm0 + wm + mt * 16 + lq * 4 + r;
#pragma unroll
      for (int nt = 0; nt < 4; ++nt) {
        const int n = tn0 + wn + nt * 16 + lr;
        float v = acc[mt][nt][r];
        v += (epi == 0) ? bias[n] : bias[mm];
        C[(size_t)mm * N + n] = f2bf(v);
      }
    }
}

// ---------------------------------------------------------------------------
// gemm256: 256x256-tile 8-phase GEMM, C = A[M,K] @ B[N,K]^T (+ epilogue).
// 512 threads = 8 waves (2M x 4N), per-wave output 128x64, BK=64, 2 K-tiles
// per iteration. LDS 128 KiB. T1+T2+T3/T4+T5. EPI 2 = bitmask+relu bf16.
// ---------------------------------------------------------------------------
template <int EPI>
__global__ void __launch_bounds__(512, 2)
gemm256(const unsigned short* __restrict__ A, const unsigned short* __restrict__ B,
        void* __restrict__ Cout, const unsigned int* __restrict__ mbits,
        int M, int N, int K,
        long long strA, long long strB, long long strC, long long strM) {
  __shared__ unsigned short sA[2][256][64];
  __shared__ unsigned short sB[2][256][64];

  // T1: bijective XCD swizzle over flattened grid (gridDim.x % 8 == 0 here)
  int lin = blockIdx.x;
  lin = (lin & 7) * ((int)gridDim.x >> 3) + (lin >> 3);
  const int tilesN = N >> 8;
  const int tilesM = M >> 8;
  const int bx = lin % tilesN;
  const int by = (lin / tilesN) % tilesM;
  const int bz = lin / (tilesN * tilesM);

  const int tn0 = bx << 8, tm0 = by << 8;
  const unsigned short* Ab = A + (size_t)bz * strA;
  const unsigned short* Bb = B + (size_t)bz * strB;

  const int tid  = threadIdx.x;
  const int lane = tid & 63;
  const int w    = tid >> 6;   // 0..7
  const int wr   = w >> 2;     // 0..1 (M)
  const int wc   = w & 3;      // 0..3 (N)
  const int lr   = lane & 15;
  const int lq   = lane >> 4;

  const int srow = tid >> 3;                          // 0..63
  const int scol = (((tid & 7) ^ (srow & 7)) << 3);   // element offset in row
  const int sdst = tid << 4;                          // byte offset in slab

#define STAGE64(bufbase, g, t0, k0, R0)                                      \
  async_load16((g) + (size_t)((t0) + (R0) + srow) * K + (k0) + scol,         \
               (char*)(bufbase) + ((R0) << 7) + sdst)

  const int sxor  = (lr & 7) << 4;
  const int k0off = (lq << 4) ^ sxor;           // kk=0 byte-in-row
  const int k1off = (64 | (lq << 4)) ^ sxor;    // kk=1 byte-in-row
  const int aRow  = (wr * 128 + lr) * 128;      // byte
  const int bRow  = (wc * 64 + lr) * 128;       // byte

#define LDA(d, mh, mt2, kk)                                                  \
  (*(const bf16x8*)((const char*)sA[d] + aRow + (mh) * 8192 + (mt2) * 2048 + \
                    k##kk##off))
#define LDB(d, nh, nt2, kk)                                                  \
  (*(const bf16x8*)((const char*)sB[d] + bRow + (nh) * 4096 + (nt2) * 2048 + \
                    k##kk##off))

  f32x4 acc[8][4] = {};
  bf16x8 afr[4][2];   // current m-half of current tile
  bf16x8 bfr[4][2];   // both n-halves of current tile (abs nt index)

#define RDA(d, mh)                                                           \
  _Pragma("unroll") for (int mt2 = 0; mt2 < 4; ++mt2) {                      \
    afr[mt2][0] = LDA(d, mh, mt2, 0);                                        \
    afr[mt2][1] = LDA(d, mh, mt2, 1);                                        \
  }
#define RDB(d, nh)                                                           \
  _Pragma("unroll") for (int nt2 = 0; nt2 < 2; ++nt2) {                      \
    bfr[(nh) * 2 + nt2][0] = LDB(d, nh, nt2, 0);                             \
    bfr[(nh) * 2 + nt2][1] = LDB(d, nh, nt2, 1);                             \
  }
#define MFMAQ(mh, nh)                                                        \
  __builtin_amdgcn_s_setprio(1);                                             \
  _Pragma("unroll") for (int mt2 = 0; mt2 < 4; ++mt2)                        \
  _Pragma("unroll") for (int nt2 = 0; nt2 < 2; ++nt2) {                      \
    acc[(mh) * 4 + mt2][(nh) * 2 + nt2] =                                    \
        __builtin_amdgcn_mfma_f32_16x16x32_bf16(                             \
            afr[mt2][0], bfr[(nh) * 2 + nt2][0],                             \
            acc[(mh) * 4 + mt2][(nh) * 2 + nt2], 0, 0, 0);                   \
    acc[(mh) * 4 + mt2][(nh) * 2 + nt2] =                                    \
        __builtin_amdgcn_mfma_f32_16x16x32_bf16(                             \
            afr[mt2][1], bfr[(nh) * 2 + nt2][1],                             \
            acc[(mh) * 4 + mt2][(nh) * 2 + nt2], 0, 0, 0);                   \
  }                                                                          \
  __builtin_amdgcn_s_setprio(0);
#define BAR __builtin_amdgcn_s_barrier()

  const int nIter = K >> 7;   // 2 K-tiles of 64 per iteration

  // prologue: B(t0) -> sB0, A(t0) -> sA0, B(t1) -> sB1 (12 issues)
  STAGE64(sB[0], Bb, tn0, 0, 0);   STAGE64(sB[0], Bb, tn0, 0, 64);
  STAGE64(sB[0], Bb, tn0, 0, 128); STAGE64(sB[0], Bb, tn0, 0, 192);
  STAGE64(sA[0], Ab, tm0, 0, 0);   STAGE64(sA[0], Ab, tm0, 0, 64);
  STAGE64(sA[0], Ab, tm0, 0, 128); STAGE64(sA[0], Ab, tm0, 0, 192);
  STAGE64(sB[1], Bb, tn0, 64, 0);  STAGE64(sB[1], Bb, tn0, 64, 64);
  STAGE64(sB[1], Bb, tn0, 64, 128);STAGE64(sB[1], Bb, tn0, 64, 192);
  asm volatile("s_waitcnt vmcnt(4)" ::: "memory");  // tile0 A+B landed
  BAR;

  for (int j = 0; j < nIter; ++j) {
    const int kb = j << 7;              // k of even tile of this pair
    const bool pf = (j + 1 < nIter);    // prefetch tiles kt+2/kt+3 valid
    // ---- p1: tile kt (buf0) quad(mh0,nh0); stage A(kt+1) h0 -> sA1
    RDA(0, 0); RDB(0, 0);
    STAGE64(sA[1], Ab, tm0, kb + 64, 0);
    STAGE64(sA[1], Ab, tm0, kb + 64, 64);
    BAR; MFMAQ(0, 0); BAR;
    // ---- p2: quad(mh0,nh1); stage A(kt+1) h1
    RDB(0, 1);
    STAGE64(sA[1], Ab, tm0, kb + 64, 128);
    STAGE64(sA[1], Ab, tm0, kb + 64, 192);
    BAR; MFMAQ(0, 1); BAR;
    // ---- p3: quad(mh1,nh1); stage B(kt+2) h0 -> sB0 (B0 free after p2)
    RDA(0, 1);
    if (pf) { STAGE64(sB[0], Bb, tn0, kb + 128, 0);
              STAGE64(sB[0], Bb, tn0, kb + 128, 64); }
    BAR; MFMAQ(1, 1); BAR;
    // ---- p4: quad(mh1,nh0) (b held from p1); stage B(kt+2) h1; gate tile kt+1
    if (pf) { STAGE64(sB[0], Bb, tn0, kb + 128, 128);
              STAGE64(sB[0], Bb, tn0, kb + 128, 192); }
    BAR; MFMAQ(1, 0);
    if (pf) asm volatile("s_waitcnt vmcnt(4)" ::: "memory");
    else    asm volatile("s_waitcnt vmcnt(0)" ::: "memory");
    BAR;
    // ---- p5: tile kt+1 (buf1) quad(mh0,nh0); stage A(kt+2) h0 -> sA0
    RDA(1, 0); RDB(1, 0);
    if (pf) { STAGE64(sA[0], Ab, tm0, kb + 128, 0);
              STAGE64(sA[0], Ab, tm0, kb + 128, 64); }
    BAR; MFMAQ(0, 0); BAR;
    // ---- p6: quad(mh0,nh1); stage A(kt+2) h1
    RDB(1, 1);
    if (pf) { STAGE64(sA[0], Ab, tm0, kb + 128, 128);
              STAGE64(sA[0], Ab, tm0, kb + 128, 192); }
    BAR; MFMAQ(0, 1); BAR;
    // ---- p7: quad(mh1,nh1); stage B(kt+3) h0 -> sB1 (B1 free after p6)
    RDA(1, 1);
    if (pf) { STAGE64(sB[1], Bb, tn0, kb + 192, 0);
              STAGE64(sB[1], Bb, tn0, kb + 192, 64); }
    BAR; MFMAQ(1, 1); BAR;
    // ---- p8: quad(mh1,nh0); stage B(kt+3) h1; gate next p1 (tile kt+2)
    if (pf) { STAGE64(sB[1], Bb, tn0, kb + 192, 128);
              STAGE64(sB[1], Bb, tn0, kb + 192, 192); }
    BAR; MFMAQ(1, 0);
    asm volatile("s_waitcnt vmcnt(4)" ::: "memory");
    BAR;
  }

  // epilogue: per thread 8x4 fragments x 4 rows
#pragma unroll
  for (int mt = 0; mt < 8; ++mt) {
#pragma unroll
    for (int r = 0; r < 4; ++r) {
      const int m = tm0 + wr * 128 + mt * 16 + lq * 4 + r;
      unsigned long long w64 = 0;
      if constexpr (EPI == 2) {
        w64 = *(const unsigned long long*)&mbits[(size_t)bz * strM +
                                                 (size_t)m * (N >> 5) +
                                                 ((tn0 + wc * 64) >> 5)];
      }
#pragma unroll
      for (int nt = 0; nt < 4; ++nt) {
        const int n = tn0 + wc * 64 + nt * 16 + lr;
        float v = acc[mt][nt][r];
        if constexpr (EPI == 2) {
          v = ((w64 >> (nt * 16 + lr)) & 1ull) ? fmaxf(v, 0.f) : 0.f;
          ((unsigned short*)Cout)[(size_t)bz * strC + (size_t)m * N + n] = f2bf(v);
        } else {
          ((float*)Cout)[(size_t)bz * strC + (size_t)m * N + n] = v;
        }
      }
    }
  }
#undef STAGE64
#undef LDA
#undef LDB
#undef RDA
#undef RDB
#undef MFMAQ
#undef BAR
}

// ---------------------------------------------------------------------------
// outgemm: 8-phase GEMM at BM=256 x BN=128, C = A[M,K] @ B[N,K]^T, fp32 out.
// 512 threads = 8 waves (2M x 4N), per-wave output 128x32, BK=64, 2 K-tiles
// per iteration. LDS 96 KiB (sA 2x[256][64], sB 2x[128][64]).
// Stage calls per K-tile: A=4, B=2 -> counted vmcnt(2) at p4/p8 (2 half-tiles
// in flight), prologue vmcnt(2), drain-0 only at last-iter p4.
// ---------------------------------------------------------------------------
__global__ void __launch_bounds__(512, 2)
outgemm(const unsigned short* __restrict__ A, const unsigned short* __restrict__ B,
        float* __restrict__ Cout, int M, int N, int K,
        long long strA, long long strB, long long strC) {
  __shared__ unsigned short sA[2][256][64];
  __shared__ unsigned short sB[2][128][64];

  // T1: bijective XCD swizzle (gridDim.x = 256, % 8 == 0)
  int lin = blockIdx.x;
  lin = (lin & 7) * ((int)gridDim.x >> 3) + (lin >> 3);
  const int tilesN = N >> 7;   // BN=128
  const int tilesM = M >> 8;   // BM=256
  const int bx = lin % tilesN;
  const int by = (lin / tilesN) % tilesM;
  const int bz = lin / (tilesN * tilesM);

  const int tn0 = bx << 7, tm0 = by << 8;
  const unsigned short* Ab = A + (size_t)bz * strA;
  const unsigned short* Bb = B + (size_t)bz * strB;

  const int tid  = threadIdx.x;
  const int lane = tid & 63;
  const int w    = tid >> 6;   // 0..7
  const int wr   = w >> 2;     // 0..1 (M half: 128 rows)
  const int wc   = w & 3;      // 0..3 (N quarter: 32 cols)
  const int lr   = lane & 15;
  const int lq   = lane >> 4;

  const int srow = tid >> 3;                          // 0..63
  const int scol = (((tid & 7) ^ (srow & 7)) << 3);   // element offset in row
  const int sdst = tid << 4;                          // byte offset in slab

#define OST(bufbase, g, t0, k0, R0)                                          \
  async_load16((g) + (size_t)((t0) + (R0) + srow) * K + (k0) + scol,         \
               (char*)(bufbase) + ((R0) << 7) + sdst)

  const int sxor  = (lr & 7) << 4;
  const int k0off = (lq << 4) ^ sxor;
  const int k1off = (64 | (lq << 4)) ^ sxor;
  const int aRow  = (wr * 128 + lr) * 128;    // byte, within [256][64] slab
  const int bRow  = (wc * 32 + lr) * 128;     // byte, within [128][64] slab

#define OLDA(d, mh, mt2, kk)                                                 \
  (*(const bf16x8*)((const char*)sA[d] + aRow + (mh) * 8192 + (mt2) * 2048 + \
                    k##kk##off))
#define OLDB(d, nt, kk)                                                      \
  (*(const bf16x8*)((const char*)sB[d] + bRow + (nt) * 2048 + k##kk##off))

  f32x4 acc[8][2] = {};
  bf16x8 afr[4][2];   // current m-half fragments
  bf16x8 bfr[2][2];   // both nt of current tile

#define ORDA(d, mh)                                                          \
  _Pragma("unroll") for (int mt2 = 0; mt2 < 4; ++mt2) {                      \
    afr[mt2][0] = OLDA(d, mh, mt2, 0);                                       \
    afr[mt2][1] = OLDA(d, mh, mt2, 1);                                       \
  }
#define ORDB(d, nt)                                                          \
  { bfr[nt][0] = OLDB(d, nt, 0); bfr[nt][1] = OLDB(d, nt, 1); }
#define OMFMAQ(mh, nt)                                                       \
  __builtin_amdgcn_s_setprio(1);                                             \
  _Pragma("unroll") for (int mt2 = 0; mt2 < 4; ++mt2) {                      \
    acc[(mh) * 4 + mt2][nt] = __builtin_amdgcn_mfma_f32_16x16x32_bf16(       \
        afr[mt2][0], bfr[nt][0], acc[(mh) * 4 + mt2][nt], 0, 0, 0);          \
    acc[(mh) * 4 + mt2][nt] = __builtin_amdgcn_mfma_f32_16x16x32_bf16(       \
        afr[mt2][1], bfr[nt][1], acc[(mh) * 4 + mt2][nt], 0, 0, 0);          \
  }                                                                          \
  __builtin_amdgcn_s_setprio(0);
#define OBAR __builtin_amdgcn_s_barrier()

  const int nIter = K >> 7;   // 2 K-tiles of 64 per iteration (K=4096 -> 32)

  // prologue: B(t0)x2 -> sB0, A(t0)x4 -> sA0, B(t1)x2 -> sB1 (8 issues)
  OST(sB[0], Bb, tn0, 0, 0);   OST(sB[0], Bb, tn0, 0, 64);
  OST(sA[0], Ab, tm0, 0, 0);   OST(sA[0], Ab, tm0, 0, 64);
  OST(sA[0], Ab, tm0, 0, 128); OST(sA[0], Ab, tm0, 0, 192);
  OST(sB[1], Bb, tn0, 64, 0);  OST(sB[1], Bb, tn0, 64, 64);
  asm volatile("s_waitcnt vmcnt(2)" ::: "memory");  // tile0 A+B landed
  OBAR;

  for (int j = 0; j < nIter; ++j) {
    const int kb = j << 7;
    const bool pf = (j + 1 < nIter);
    // ---- p1: tile kt (buf0) quad(mh0,nt0); stage A(kt+1) h0 -> sA1
    ORDA(0, 0); ORDB(0, 0);
    OST(sA[1], Ab, tm0, kb + 64, 0);
    OST(sA[1], Ab, tm0, kb + 64, 64);
    OBAR; OMFMAQ(0, 0); OBAR;
    // ---- p2: quad(mh0,nt1); stage A(kt+1) h1
    ORDB(0, 1);
    OST(sA[1], Ab, tm0, kb + 64, 128);
    OST(sA[1], Ab, tm0, kb + 64, 192);
    OBAR; OMFMAQ(0, 1); OBAR;
    // ---- p3: quad(mh1,nt1); stage B(kt+2) h0 -> sB0 (B0 free after p2)
    ORDA(0, 1);
    if (pf) OST(sB[0], Bb, tn0, kb + 128, 0);
    OBAR; OMFMAQ(1, 1); OBAR;
    // ---- p4: quad(mh1,nt0) (b held from p1); stage B(kt+2) h1; gate kt+1
    if (pf) OST(sB[0], Bb, tn0, kb + 128, 64);
    OBAR; OMFMAQ(1, 0);
    if (pf) asm volatile("s_waitcnt vmcnt(2)" ::: "memory");
    else    asm volatile("s_waitcnt vmcnt(0)" ::: "memory");
    OBAR;
    // ---- p5: tile kt+1 (buf1) quad(mh0,nt0); stage A(kt+2) h0 -> sA0
    ORDA(1, 0); ORDB(1, 0);
    if (pf) { OST(sA[0], Ab, tm0, kb + 128, 0);
              OST(sA[0], Ab, tm0, kb + 128, 64); }
    OBAR; OMFMAQ(0, 0); OBAR;
    // ---- p6: quad(mh0,nt1); stage A(kt+2) h1
    ORDB(1, 1);
    if (pf) { OST(sA[0], Ab, tm0, kb + 128, 128);
              OST(sA[0], Ab, tm0, kb + 128, 192); }
    OBAR; OMFMAQ(0, 1); OBAR;
    // ---- p7: quad(mh1,nt1); stage B(kt+3) h0 -> sB1 (B1 free after p6)
    ORDA(1, 1);
    if (pf) OST(sB[1], Bb, tn0, kb + 192, 0);
    OBAR; OMFMAQ(1, 1); OBAR;
    // ---- p8: quad(mh1,nt0); stage B(kt+3) h1; gate next p1 (tile kt+2)
    if (pf) OST(sB[1], Bb, tn0, kb + 192, 64);
    OBAR; OMFMAQ(1, 0);
    asm volatile("s_waitcnt vmcnt(2)" ::: "memory");
    OBAR;
  }

  // epilogue: fp32 store. per thread 8x2 fragments x 4 rows
#pragma unroll
  for (int mt = 0; mt < 8; ++mt) {
#pragma unroll
    for (int r = 0; r < 4; ++r) {
      const int m = tm0 + wr * 128 + mt * 16 + lq * 4 + r;
#pragma unroll
      for (int nt = 0; nt < 2; ++nt) {
        const int n = tn0 + wc * 32 + nt * 16 + lr;
        Cout[(size_t)bz * strC + (size_t)m * N + n] = acc[mt][nt][r];
      }
    }
  }
#undef OST
#undef OLDA
#undef OLDB
#undef ORDA
#undef ORDB
#undef OMFMAQ
#undef OBAR
}

extern "C" void kernel_launch(void* const* d_in, const int* in_sizes, int n_in,
                              void* d_out, int out_size, void* d_ws, size_t ws_size,
                              hipStream_t stream) {
  const float* query = (const float*)d_in[0];
  const float* key   = (const float*)d_in[1];
  const float* value = (const float*)d_in[2];
  const int*   mask  = (const int*)d_in[3];
  const float* W1    = (const float*)d_in[4];
  const float* b1    = (const float*)d_in[5];
  const float* W2    = (const float*)d_in[6];
  const float* b2    = (const float*)d_in[7];
  float* out = (float*)d_out;

  constexpr int B = 4, S = 4096, E = 512;
  constexpr long long BSE = (long long)B * S * E;
  constexpr long long SE  = (long long)S * E;
  constexpr long long SS  = (long long)S * S;
  constexpr long long BSS = (long long)B * S * S;
  constexpr long long EE  = (long long)E * E;

  char* ws = (char*)d_ws;
  unsigned short* Qb   = (unsigned short*)ws;  ws += BSE * 2;
  unsigned short* Kb   = (unsigned short*)ws;  ws += BSE * 2;
  unsigned short* Vb   = (unsigned short*)ws;  ws += BSE * 2;
  unsigned short* W1b  = (unsigned short*)ws;  ws += EE * 2;
  unsigned short* W2b  = (unsigned short*)ws;  ws += EE * 2;
  unsigned short* Kp   = (unsigned short*)ws;  ws += BSE * 2;   // [B*S, E]
  unsigned short* Vpt  = (unsigned short*)ws;  ws += BSE * 2;   // [B][E][S]
  unsigned short* alph = (unsigned short*)ws;  ws += BSS * 2;   // [B][S][S]
  unsigned int*   mbit = (unsigned int*)ws;    ws += BSS / 8;   // [B][S][S/32]

  // converts + mask packing, one launch
  prep<<<dim3(24576 + 512 + 65536), 256, 0, stream>>>(
      query, key, value, W1, W2, mask, Qb, Kb, Vb, W1b, W2b, mbit);

  // both projections, one launch (1024 blocks = 4/CU)
  proj<<<dim3(1024), 256, 0, stream>>>(Kb, W1b, Kp, b1, W2b, Vb, Vpt, b2);

  // alpha = bitmask-relu(Qb @ Kp^T)  (M=N=S, K=E, per batch) — 256^2 8-phase
  gemm256<2><<<dim3((S / 256) * (S / 256) * B), 512, 0, stream>>>(
      Qb, Kp, alph, mbit, S, S, E, SE, SE, SS, SS / 32);

  // out = alpha @ Vpt^T  (M=S, N=E, K=S, per batch) — 8-phase 256x128
  outgemm<<<dim3((E / 128) * (S / 256) * B), 512, 0, stream>>>(
      alph, Vpt, out, S, E, S, SS, SE, SE);
}